// Round 15
// baseline (54.174 us; speedup 1.0000x reference)
//
#include <hip/hip_runtime.h>
#include <math.h>

// PersistenceLoss: BCE(y_true, y_pred) + 0.005 * topo
// topo: per 64x64 patch sort both tensors' values, mean squared diff of
// aligned order statistics. B=64, H=W=512 -> 4096 patches of 4096 elems.
//
// COUNTING-SORT + EVENT-HISTOGRAM (no sorts, no dependent walks):
//   Quantize to NB=1024 uniform bins (monotone; topo abs err ~1e-7 << 2e-2).
//   Per patch (one 1024-thread block, 4 elems/thread):
//     1. LDS histograms HA,HB (atomics), E zeroed in same pass
//     2. packed block-scan, EXACTLY 1 bin/thread -> CDFs in registers
//        (reads SH[t], SH[NB+t]: stride-4B, conflict-free)
//     3. scatter events E[CA]+=1, E[CB]-=1
//     4. block-scan of E, EXACTLY 1 int4/thread at E[4t] (16B stride,
//        conflict-free) -> D(r); topo = sum D(r)^2
//   Identity: QA(r) = #{a : CA(a) <= r} = prefix_sum(events)(r).
//   BCE fused into load. Two-kernel finish (R12 lesson: same-address device
//   atomics + fence serialize cross-XCD ~150us; a 2nd launch is cheaper).

#define THREADS 1024
#define NB 1024
#define PATCH_N 4096
#define NBLOCKS 4096

typedef unsigned int u32;

__global__ __launch_bounds__(THREADS) void patch_hist_kernel(
    const float* __restrict__ y_true,
    const float* __restrict__ y_pred,
    float2* __restrict__ partials)
{
    __shared__ int SH[2 * NB];      // HA = SH[0..NB), HB = SH[NB..2NB)
    __shared__ int E[4100];         // event array over ranks 0..4096
    __shared__ u32 wsum[16];        // packed per-wave totals (A<<16 | B)
    __shared__ int wsumE[16];
    __shared__ float rsum[32];

    const int bp = blockIdx.x;       // patch id 0..4095
    const int bb = bp >> 6;          // batch index
    const int p  = bp & 63;          // patch within image
    const int pr = p >> 3;
    const int pc = p & 7;
    const size_t base = (size_t)bb * (512 * 512)
                      + (size_t)pr * (64 * 512)
                      + (size_t)pc * 64;
    const int t = threadIdx.x;
    const int lane = t & 63;
    const int wid  = t >> 6;         // 0..15

    // ---- zero hist + event arrays (vectorized, conflict-free) ----
    {
        int4 z = make_int4(0, 0, 0, 0);
        if (t < 512) reinterpret_cast<int4*>(SH)[t] = z;   // 2048 ints
        reinterpret_cast<int4*>(E)[t] = z;                 // 4096 ints
        if (t == 0) E[4096] = 0;
    }
    __syncthreads();

    // ---- load 4 elems/thread: fused BCE + histogram build ----
    // 16 threads per 64-float row: row = t>>4, col = (t&15)*4 (16B stride:
    // perfectly coalesced float4 loads)
    const size_t rowbase = base + (size_t)(t >> 4) * 512 + (size_t)(t & 15) * 4;
    float bce = 0.0f;
    {
        float4 va = *reinterpret_cast<const float4*>(y_true + rowbase);
        float4 vb = *reinterpret_cast<const float4*>(y_pred + rowbase);
        float ya[4] = {va.x, va.y, va.z, va.w};
        float yb[4] = {vb.x, vb.y, vb.z, vb.w};
        #pragma unroll
        for (int i = 0; i < 4; ++i) {
            float yt = ya[i], yp = yb[i];
            float pcl = fminf(fmaxf(yp, 1e-7f), 1.0f - 1e-7f);
            // log1pf(-p) == logf(1-p): Sterbenz-exact for p>=0.5; __logf =
            // v_log_f32 + mul. BCE abs err ~1e-6 << threshold.
            float L1 = __logf(pcl);
            float L0 = __logf(1.0f - pcl);
            bce -= L0 + yt * (L1 - L0);
            // v_cvt_u32_f32 saturates negatives to 0; yt,yp < 1 so *NB < NB.
            unsigned ba = min((unsigned)(yt * (float)NB), NB - 1u);
            unsigned bn = min((unsigned)(yp * (float)NB), NB - 1u);
            atomicAdd(&SH[ba], 1);
            atomicAdd(&SH[NB + bn], 1);
        }
    }
    __syncthreads();

    // ---- packed CDF scan: thread t owns bin t of both hists ----
    // packed value = (A << 16) | B; partial sums <= 4096 -> no carry.
    const u32 v = ((u32)SH[t] << 16) | (u32)SH[NB + t];
    u32 ss = v;
    #pragma unroll
    for (int off = 1; off < 64; off <<= 1) {
        u32 x = __shfl_up(ss, off, 64);
        if (lane >= off) ss += x;
    }
    if (lane == 63) wsum[wid] = ss;
    __syncthreads();
    u32 wb = 0;
    #pragma unroll
    for (int w = 0; w < 15; ++w)
        if (wid > w) wb += wsum[w];
    const u32 cdf = wb + ss;          // inclusive packed CDF at bin t

    // ---- scatter events (E disjoint from SH: no extra barrier) ----
    atomicAdd(&E[cdf >> 16], 1);
    atomicAdd(&E[cdf & 0xFFFFu], -1);
    __syncthreads();

    // ---- inclusive scan of E over r=0..4095; topo += D(r)^2 ----
    // thread t owns ranks [4t, 4t+4): one int4 at 16B stride (conflict-free)
    int4 e = reinterpret_cast<const int4*>(E)[t];
    int el0 = e.x;
    int el1 = el0 + e.y;
    int el2 = el1 + e.z;
    int el3 = el2 + e.w;
    int ess = el3;
    #pragma unroll
    for (int off = 1; off < 64; off <<= 1) {
        int x = __shfl_up(ess, off, 64);
        if (lane >= off) ess += x;
    }
    if (lane == 63) wsumE[wid] = ess;
    __syncthreads();
    int ewb = 0;
    #pragma unroll
    for (int w = 0; w < 15; ++w)
        if (wid > w) ewb += wsumE[w];
    const int ebase = ewb + ess - el3;    // exclusive base for this thread
    float sq;
    {
        float d0 = (float)(ebase + el0);
        float d1 = (float)(ebase + el1);
        float d2 = (float)(ebase + el2);
        float d3 = (float)(ebase + el3);
        sq = d0 * d0;
        sq = fmaf(d1, d1, sq);
        sq = fmaf(d2, d2, sq);
        sq = fmaf(d3, d3, sq);
    }

    // ---- block reduction ----
    #pragma unroll
    for (int off = 32; off >= 1; off >>= 1) {
        bce += __shfl_down(bce, off, 64);
        sq  += __shfl_down(sq, off, 64);
    }
    __syncthreads();
    if (lane == 0) { rsum[wid] = bce; rsum[16 + wid] = sq; }
    __syncthreads();
    if (t == 0) {
        float bsum = 0.0f, qsum = 0.0f;
        #pragma unroll
        for (int w = 0; w < 16; ++w) { bsum += rsum[w]; qsum += rsum[16 + w]; }
        const float inv_nb2 = 1.0f / ((float)NB * (float)NB);
        partials[bp] = make_float2(bsum, qsum * inv_nb2);
    }
}

__global__ __launch_bounds__(256) void final_reduce_kernel(
    const float2* __restrict__ partials,
    float* __restrict__ out)
{
    __shared__ float rb[256];
    __shared__ float rs[256];
    const int tid = threadIdx.x;
    float bsum = 0.0f, ssum = 0.0f;
    for (int i = tid; i < NBLOCKS; i += 256) {
        float2 v = partials[i];
        bsum += v.x;
        ssum += v.y;
    }
    rb[tid] = bsum;
    rs[tid] = ssum;
    __syncthreads();
    for (int off = 128; off > 0; off >>= 1) {
        if (tid < off) {
            rb[tid] += rb[tid + off];
            rs[tid] += rs[tid + off];
        }
        __syncthreads();
    }
    if (tid == 0) {
        // BCE mean and topo mean share denominator 64*512*512 = 16777216
        out[0] = (rb[0] + 0.005f * rs[0]) * (1.0f / 16777216.0f);
    }
}

extern "C" void kernel_launch(void* const* d_in, const int* in_sizes, int n_in,
                              void* d_out, int out_size, void* d_ws, size_t ws_size,
                              hipStream_t stream) {
    const float* y_true = (const float*)d_in[0];
    const float* y_pred = (const float*)d_in[1];
    float* out = (float*)d_out;
    float2* partials = (float2*)d_ws;   // 4096 * 8 B = 32 KB

    hipLaunchKernelGGL(patch_hist_kernel, dim3(NBLOCKS), dim3(THREADS), 0, stream,
                       y_true, y_pred, partials);
    hipLaunchKernelGGL(final_reduce_kernel, dim3(1), dim3(256), 0, stream,
                       partials, out);
}

// Round 16
// 37.294 us; speedup vs baseline: 1.4526x; 1.4526x over previous
//
#include <hip/hip_runtime.h>
#include <math.h>

// PersistenceLoss: BCE(y_true, y_pred) + 0.005 * topo
// topo: per 64x64 patch sort both tensors' values, mean squared diff of
// aligned order statistics. B=64, H=W=512 -> 4096 patches of 4096 elems.
//
// COUNTING-SORT + EVENT-HISTOGRAM (no sorts, no dependent walks):
//   Quantize to NB=1024 uniform bins (monotone; topo abs err ~1e-7 << 2e-2).
//   Per patch (one 512-thread block — R15 lesson: 1024-thread blocks leave
//   2 blocks/CU and expose every barrier; 512x4 blocks/CU hides them):
//     1. LDS histograms HA,HB (atomics), E zeroed in same initial pass
//     2. packed block-scan (2 bins/thread) -> inclusive CDFs in registers
//     3. scatter events E[CA]+=1, E[CB]-=1 (separate array: no barrier
//        between scan and scatter)
//     4. block-scan of E (8 ranks/thread) -> D(r); topo = sum D(r)^2
//   Identity: QA(r) = #{a : CA(a) <= r} = prefix_sum(events)(r).
//   BCE fused into load. Two-kernel finish (R12 lesson: same-address device
//   atomics + fence serialize cross-XCD ~150us; a 2nd launch is cheaper).

#define THREADS 512
#define NB 1024
#define PATCH_N 4096
#define NBLOCKS 4096

typedef unsigned int u32;

__global__ __launch_bounds__(THREADS) void patch_hist_kernel(
    const float* __restrict__ y_true,
    const float* __restrict__ y_pred,
    float2* __restrict__ partials)
{
    __shared__ int SH[2 * NB];      // HA = SH[0..NB), HB = SH[NB..2NB)
    __shared__ int E[4100];         // event array over ranks 0..4096
    __shared__ u32 wsum[8];         // packed per-wave totals (A<<16 | B)
    __shared__ int wsumE[8];
    __shared__ float rsum[16];

    const int bp = blockIdx.x;       // patch id 0..4095
    const int bb = bp >> 6;          // batch index
    const int p  = bp & 63;          // patch within image
    const int pr = p >> 3;
    const int pc = p & 7;
    const size_t base = (size_t)bb * (512 * 512)
                      + (size_t)pr * (64 * 512)
                      + (size_t)pc * 64;
    const int t = threadIdx.x;
    const int lane = t & 63;
    const int wid  = t >> 6;         // 0..7

    // ---- zero hist + event arrays in one vectorized pass ----
    {
        int4 z = make_int4(0, 0, 0, 0);
        reinterpret_cast<int4*>(SH)[t] = z;            // 2048 ints
        reinterpret_cast<int4*>(E)[t] = z;             // first 2048 ints
        reinterpret_cast<int4*>(E)[t + 512] = z;       // next 2048 ints
        if (t == 0) E[4096] = 0;
    }
    __syncthreads();

    // ---- load 8 elems/thread: fused BCE + histogram build ----
    // 8 threads per 64-float row: row = t>>3, col = (t&7)*8
    const size_t rowbase = base + (size_t)(t >> 3) * 512 + (size_t)(t & 7) * 8;
    float bce = 0.0f;
    #pragma unroll
    for (int q = 0; q < 2; ++q) {
        float4 va = *reinterpret_cast<const float4*>(y_true + rowbase + q * 4);
        float4 vb = *reinterpret_cast<const float4*>(y_pred + rowbase + q * 4);
        float ya[4] = {va.x, va.y, va.z, va.w};
        float yb[4] = {vb.x, vb.y, vb.z, vb.w};
        #pragma unroll
        for (int i = 0; i < 4; ++i) {
            float yt = ya[i], yp = yb[i];
            float pcl = fminf(fmaxf(yp, 1e-7f), 1.0f - 1e-7f);
            // log1pf(-p) == logf(1-p): Sterbenz-exact for p>=0.5; __logf =
            // v_log_f32 + mul. BCE abs err ~1e-6 << threshold.
            float L1 = __logf(pcl);
            float L0 = __logf(1.0f - pcl);
            bce -= L0 + yt * (L1 - L0);
            // v_cvt_u32_f32 saturates negatives to 0; values < 1 so *NB < NB
            unsigned ba = min((unsigned)(yt * (float)NB), NB - 1u);
            unsigned bn = min((unsigned)(yp * (float)NB), NB - 1u);
            atomicAdd(&SH[ba], 1);
            atomicAdd(&SH[NB + bn], 1);
        }
    }
    __syncthreads();

    // ---- packed CDF scan: thread t owns bins {2t, 2t+1} of both hists ----
    // packed value = (A << 16) | B; partial sums <= 4096 -> no carry.
    u32 v0 = ((u32)SH[2 * t] << 16)     | (u32)SH[NB + 2 * t];
    u32 v1 = ((u32)SH[2 * t + 1] << 16) | (u32)SH[NB + 2 * t + 1];
    u32 s = v0 + v1;
    u32 ss = s;
    #pragma unroll
    for (int off = 1; off < 64; off <<= 1) {
        u32 v = __shfl_up(ss, off, 64);
        if (lane >= off) ss += v;
    }
    if (lane == 63) wsum[wid] = ss;
    __syncthreads();
    u32 wb = 0;
    #pragma unroll
    for (int w = 0; w < 7; ++w)
        if (wid > w) wb += wsum[w];
    const u32 basex = wb + ss - s;    // packed exclusive base for this thread
    const u32 cdf0 = basex + v0;      // inclusive CDF at bin 2t
    const u32 cdf1 = basex + v0 + v1; // inclusive CDF at bin 2t+1

    // ---- scatter events (E disjoint from SH: no barrier needed) ----
    atomicAdd(&E[cdf0 >> 16], 1);
    atomicAdd(&E[cdf0 & 0xFFFFu], -1);
    atomicAdd(&E[cdf1 >> 16], 1);
    atomicAdd(&E[cdf1 & 0xFFFFu], -1);
    __syncthreads();

    // ---- inclusive scan of E over r=0..4095; topo += D(r)^2 ----
    // thread t owns r in [t*8, t*8+8)
    int el[8];
    {
        const int4* ep = reinterpret_cast<const int4*>(E + t * 8);
        int4 e0 = ep[0], e1 = ep[1];
        el[0]=e0.x; el[1]=e0.y; el[2]=e0.z; el[3]=e0.w;
        el[4]=e1.x; el[5]=e1.y; el[6]=e1.z; el[7]=e1.w;
    }
    int es = 0;
    #pragma unroll
    for (int k = 0; k < 8; ++k) {
        es += el[k];
        el[k] = es;          // local inclusive
    }
    int ess = es;
    #pragma unroll
    for (int off = 1; off < 64; off <<= 1) {
        int v = __shfl_up(ess, off, 64);
        if (lane >= off) ess += v;
    }
    if (lane == 63) wsumE[wid] = ess;
    __syncthreads();
    int ewb = 0;
    #pragma unroll
    for (int w = 0; w < 7; ++w)
        if (wid > w) ewb += wsumE[w];
    const int ebase = ewb + ess - es;    // exclusive base
    float sq = 0.0f;
    #pragma unroll
    for (int k = 0; k < 8; ++k) {
        float d = (float)(ebase + el[k]);   // D(r) in bin units
        sq = fmaf(d, d, sq);
    }

    // ---- block reduction ----
    #pragma unroll
    for (int off = 32; off >= 1; off >>= 1) {
        bce += __shfl_down(bce, off, 64);
        sq  += __shfl_down(sq, off, 64);
    }
    __syncthreads();
    if (lane == 0) { rsum[wid] = bce; rsum[8 + wid] = sq; }
    __syncthreads();
    if (t == 0) {
        float bsum = 0.0f, qsum = 0.0f;
        #pragma unroll
        for (int w = 0; w < 8; ++w) { bsum += rsum[w]; qsum += rsum[8 + w]; }
        const float inv_nb2 = 1.0f / ((float)NB * (float)NB);
        partials[bp] = make_float2(bsum, qsum * inv_nb2);
    }
}

__global__ __launch_bounds__(256) void final_reduce_kernel(
    const float2* __restrict__ partials,
    float* __restrict__ out)
{
    __shared__ float rb[256];
    __shared__ float rs[256];
    const int tid = threadIdx.x;
    float bsum = 0.0f, ssum = 0.0f;
    for (int i = tid; i < NBLOCKS; i += 256) {
        float2 v = partials[i];
        bsum += v.x;
        ssum += v.y;
    }
    rb[tid] = bsum;
    rs[tid] = ssum;
    __syncthreads();
    for (int off = 128; off > 0; off >>= 1) {
        if (tid < off) {
            rb[tid] += rb[tid + off];
            rs[tid] += rs[tid + off];
        }
        __syncthreads();
    }
    if (tid == 0) {
        // BCE mean and topo mean share denominator 64*512*512 = 16777216
        out[0] = (rb[0] + 0.005f * rs[0]) * (1.0f / 16777216.0f);
    }
}

extern "C" void kernel_launch(void* const* d_in, const int* in_sizes, int n_in,
                              void* d_out, int out_size, void* d_ws, size_t ws_size,
                              hipStream_t stream) {
    const float* y_true = (const float*)d_in[0];
    const float* y_pred = (const float*)d_in[1];
    float* out = (float*)d_out;
    float2* partials = (float2*)d_ws;   // 4096 * 8 B = 32 KB

    hipLaunchKernelGGL(patch_hist_kernel, dim3(NBLOCKS), dim3(THREADS), 0, stream,
                       y_true, y_pred, partials);
    hipLaunchKernelGGL(final_reduce_kernel, dim3(1), dim3(256), 0, stream,
                       partials, out);
}

// Round 17
// 37.058 us; speedup vs baseline: 1.4619x; 1.0064x over previous
//
#include <hip/hip_runtime.h>
#include <math.h>

// PersistenceLoss: BCE(y_true, y_pred) + 0.005 * topo
// topo: per 64x64 patch sort both tensors' values, mean squared diff of
// aligned order statistics. B=64, H=W=512 -> 4096 patches of 4096 elems.
//
// COUNTING-SORT + EVENT-HISTOGRAM (no sorts, no dependent walks):
//   Quantize to NB=512 uniform bins (monotone; topo abs err ~3e-6 << 2e-2).
//   Per patch (one 512-thread block; R15 lesson: 512x4 blocks/CU hides
//   barriers, 1024x2 does not):
//     1. LDS histograms, 2-WAY PRIVATIZED (waves 0-3 -> copy0, 4-7 -> copy1)
//        to halve atomic same-bank collisions; E zeroed in same pass
//     2. packed block-scan, EXACTLY 1 bin/thread (copies merged at read,
//        all reads stride-1 conflict-free) -> inclusive CDFs in registers
//     3. scatter events E[CA]+=1, E[CB]-=1 (disjoint array: no barrier
//        between scan and scatter)
//     4. block-scan of E (8 ranks/thread) -> D(r); topo = sum D(r)^2
//   Identity: QA(r) = #{a : CA(a) <= r} = prefix_sum(events)(r).
//   BCE fused into load. Two-kernel finish (R12 lesson: same-address device
//   atomics + fence serialize cross-XCD ~150us; a 2nd launch is cheaper).

#define THREADS 512
#define NB 512
#define PATCH_N 4096
#define NBLOCKS 4096

typedef unsigned int u32;

__global__ __launch_bounds__(THREADS) void patch_hist_kernel(
    const float* __restrict__ y_true,
    const float* __restrict__ y_pred,
    float2* __restrict__ partials)
{
    // SH layout: [HA0(512) | HB0(512) | HA1(512) | HB1(512)] = 2048 ints
    __shared__ int SH[4 * NB];
    __shared__ int E[4100];         // event array over ranks 0..4096
    __shared__ u32 wsum[8];         // packed per-wave totals (A<<16 | B)
    __shared__ int wsumE[8];
    __shared__ float rsum[16];

    const int bp = blockIdx.x;       // patch id 0..4095
    const int bb = bp >> 6;          // batch index
    const int p  = bp & 63;          // patch within image
    const int pr = p >> 3;
    const int pc = p & 7;
    const size_t base = (size_t)bb * (512 * 512)
                      + (size_t)pr * (64 * 512)
                      + (size_t)pc * 64;
    const int t = threadIdx.x;
    const int lane = t & 63;
    const int wid  = t >> 6;         // 0..7

    // ---- zero hist (2048 ints) + event (4096 ints) arrays ----
    {
        int4 z = make_int4(0, 0, 0, 0);
        reinterpret_cast<int4*>(SH)[t] = z;            // 2048 ints
        reinterpret_cast<int4*>(E)[t] = z;             // first 2048 ints
        reinterpret_cast<int4*>(E)[t + 512] = z;       // next 2048 ints
        if (t == 0) E[4096] = 0;
    }
    __syncthreads();

    // ---- load 8 elems/thread: fused BCE + privatized histogram ----
    // 8 threads per 64-float row: row = t>>3, col = (t&7)*8
    const size_t rowbase = base + (size_t)(t >> 3) * 512 + (size_t)(t & 7) * 8;
    const int hoff = (t & 256) ? 2 * NB : 0;   // waves 0-3 vs 4-7
    float bce = 0.0f;
    #pragma unroll
    for (int q = 0; q < 2; ++q) {
        float4 va = *reinterpret_cast<const float4*>(y_true + rowbase + q * 4);
        float4 vb = *reinterpret_cast<const float4*>(y_pred + rowbase + q * 4);
        float ya[4] = {va.x, va.y, va.z, va.w};
        float yb[4] = {vb.x, vb.y, vb.z, vb.w};
        #pragma unroll
        for (int i = 0; i < 4; ++i) {
            float yt = ya[i], yp = yb[i];
            float pcl = fminf(fmaxf(yp, 1e-7f), 1.0f - 1e-7f);
            // log1pf(-p) == logf(1-p): Sterbenz-exact for p>=0.5; __logf =
            // v_log_f32 + mul. BCE abs err ~1e-6 << threshold.
            float L1 = __logf(pcl);
            float L0 = __logf(1.0f - pcl);
            bce -= L0 + yt * (L1 - L0);
            // v_cvt_u32_f32 saturates negatives to 0; values < 1 so *NB < NB
            unsigned ba = min((unsigned)(yt * (float)NB), NB - 1u);
            unsigned bn = min((unsigned)(yp * (float)NB), NB - 1u);
            atomicAdd(&SH[hoff + ba], 1);
            atomicAdd(&SH[hoff + NB + bn], 1);
        }
    }
    __syncthreads();

    // ---- packed CDF scan: thread t owns bin t (copies merged at read) ----
    // packed value = (A << 16) | B; partial sums <= 4096 -> no carry.
    const u32 va_ = (u32)(SH[t] + SH[2 * NB + t]);
    const u32 vb_ = (u32)(SH[NB + t] + SH[3 * NB + t]);
    const u32 v = (va_ << 16) | vb_;
    u32 ss = v;
    #pragma unroll
    for (int off = 1; off < 64; off <<= 1) {
        u32 x = __shfl_up(ss, off, 64);
        if (lane >= off) ss += x;
    }
    if (lane == 63) wsum[wid] = ss;
    __syncthreads();
    u32 wb = 0;
    #pragma unroll
    for (int w = 0; w < 7; ++w)
        if (wid > w) wb += wsum[w];
    const u32 cdf = wb + ss;          // inclusive packed CDF at bin t

    // ---- scatter events (E disjoint from SH: no barrier needed) ----
    atomicAdd(&E[cdf >> 16], 1);
    atomicAdd(&E[cdf & 0xFFFFu], -1);
    __syncthreads();

    // ---- inclusive scan of E over r=0..4095; topo += D(r)^2 ----
    // thread t owns r in [t*8, t*8+8)
    int el[8];
    {
        const int4* ep = reinterpret_cast<const int4*>(E + t * 8);
        int4 e0 = ep[0], e1 = ep[1];
        el[0]=e0.x; el[1]=e0.y; el[2]=e0.z; el[3]=e0.w;
        el[4]=e1.x; el[5]=e1.y; el[6]=e1.z; el[7]=e1.w;
    }
    int es = 0;
    #pragma unroll
    for (int k = 0; k < 8; ++k) {
        es += el[k];
        el[k] = es;          // local inclusive
    }
    int ess = es;
    #pragma unroll
    for (int off = 1; off < 64; off <<= 1) {
        int x = __shfl_up(ess, off, 64);
        if (lane >= off) ess += x;
    }
    if (lane == 63) wsumE[wid] = ess;
    __syncthreads();
    int ewb = 0;
    #pragma unroll
    for (int w = 0; w < 7; ++w)
        if (wid > w) ewb += wsumE[w];
    const int ebase = ewb + ess - es;    // exclusive base
    float sq = 0.0f;
    #pragma unroll
    for (int k = 0; k < 8; ++k) {
        float d = (float)(ebase + el[k]);   // D(r) in bin units
        sq = fmaf(d, d, sq);
    }

    // ---- block reduction ----
    #pragma unroll
    for (int off = 32; off >= 1; off >>= 1) {
        bce += __shfl_down(bce, off, 64);
        sq  += __shfl_down(sq, off, 64);
    }
    __syncthreads();
    if (lane == 0) { rsum[wid] = bce; rsum[8 + wid] = sq; }
    __syncthreads();
    if (t == 0) {
        float bsum = 0.0f, qsum = 0.0f;
        #pragma unroll
        for (int w = 0; w < 8; ++w) { bsum += rsum[w]; qsum += rsum[8 + w]; }
        const float inv_nb2 = 1.0f / ((float)NB * (float)NB);
        partials[bp] = make_float2(bsum, qsum * inv_nb2);
    }
}

__global__ __launch_bounds__(256) void final_reduce_kernel(
    const float2* __restrict__ partials,
    float* __restrict__ out)
{
    __shared__ float rb[256];
    __shared__ float rs[256];
    const int tid = threadIdx.x;
    float bsum = 0.0f, ssum = 0.0f;
    for (int i = tid; i < NBLOCKS; i += 256) {
        float2 v = partials[i];
        bsum += v.x;
        ssum += v.y;
    }
    rb[tid] = bsum;
    rs[tid] = ssum;
    __syncthreads();
    for (int off = 128; off > 0; off >>= 1) {
        if (tid < off) {
            rb[tid] += rb[tid + off];
            rs[tid] += rs[tid + off];
        }
        __syncthreads();
    }
    if (tid == 0) {
        // BCE mean and topo mean share denominator 64*512*512 = 16777216
        out[0] = (rb[0] + 0.005f * rs[0]) * (1.0f / 16777216.0f);
    }
}

extern "C" void kernel_launch(void* const* d_in, const int* in_sizes, int n_in,
                              void* d_out, int out_size, void* d_ws, size_t ws_size,
                              hipStream_t stream) {
    const float* y_true = (const float*)d_in[0];
    const float* y_pred = (const float*)d_in[1];
    float* out = (float*)d_out;
    float2* partials = (float2*)d_ws;   // 4096 * 8 B = 32 KB

    hipLaunchKernelGGL(patch_hist_kernel, dim3(NBLOCKS), dim3(THREADS), 0, stream,
                       y_true, y_pred, partials);
    hipLaunchKernelGGL(final_reduce_kernel, dim3(1), dim3(256), 0, stream,
                       partials, out);
}